// Round 4
// baseline (98.865 us; speedup 1.0000x reference)
//
#include <hip/hip_runtime.h>
#include <math.h>

#ifndef M_PI
#define M_PI 3.14159265358979323846
#endif

#define BATCHES 256
#define S_LEN   131072

// ---------------- shared helpers ----------------

__device__ __forceinline__ void compute_coeffs(float level_in, float b0[3], float na1[3], float na2[3]) {
    const float FD[3] = {270.0f, 800.0f, 2300.0f};
    const float FN[3] = {500.0f, 1500.0f, 2500.0f};
    const float FB[3] = {730.0f, 2100.0f, 3000.0f};
    float level = fminf(fmaxf(level_in, 0.0f), 1.0f);
    float t_low  = fminf(fmaxf(level * 2.0f, 0.0f), 1.0f);
    float t_high = fminf(fmaxf((level - 0.5f) * 2.0f, 0.0f), 1.0f);
    bool hi = (level >= 0.5f);
    const float W0 = (float)(2.0 * M_PI / 16000.0);
    #pragma unroll
    for (int k = 0; k < 3; ++k) {
        float f, q;
        if (hi) { f = (1.0f - t_high) * FN[k] + t_high * FB[k];
                  q = (1.0f - t_high) * 8.0f  + t_high * 12.0f; }
        else    { f = (1.0f - t_low) * FD[k] + t_low * FN[k];
                  q = (1.0f - t_low) * 5.0f  + t_low * 8.0f; }
        float omega = W0 * f;
        float sn = sinf(omega), cs = cosf(omega);
        float alpha = sn / (2.0f * fmaxf(q, 0.5f));
        float a0 = 1.0f + alpha;
        b0[k]  = alpha / a0;             // b2 == -b0 exactly
        na1[k] = (2.0f * cs) / a0;       // -a1
        na2[k] = -((1.0f - alpha) / a0); // -a2
    }
}

#define STEP3(XT, XTM2, SUMV)                                                    \
    {                                                                            \
        float d = (XT) - (XTM2);                                                 \
        float e0 = fmaf(b0[0], d, na2[0] * y2[0]);                               \
        float e1 = fmaf(b0[1], d, na2[1] * y2[1]);                               \
        float e2 = fmaf(b0[2], d, na2[2] * y2[2]);                               \
        float yy0 = fmaf(na1[0], y1[0], e0);                                     \
        float yy1 = fmaf(na1[1], y1[1], e1);                                     \
        float yy2 = fmaf(na1[2], y1[2], e2);                                     \
        y2[0] = y1[0]; y1[0] = yy0;                                              \
        y2[1] = y1[1]; y1[1] = yy1;                                              \
        y2[2] = y1[2]; y1[2] = yy2;                                              \
        SUMV = (yy0 + yy1 + yy2);                                                \
    }

__device__ __forceinline__ float agent_load(const float* p) {
    return __hip_atomic_load(p, __ATOMIC_RELAXED, __HIP_MEMORY_SCOPE_AGENT);
}
__device__ __forceinline__ void agent_store(float* p, float v) {
    __hip_atomic_store(p, v, __ATOMIC_RELAXED, __HIP_MEMORY_SCOPE_AGENT);
}

// ================= fused single-kernel path (CHUNK=32, x lives in registers) =================

#define TPB    256
#define CCH    32                 // samples per thread-chunk
#define CPRC   (S_LEN / CCH)      // 4096 chunks per row
#define SEGS   16                 // blocks per row (CPRC / TPB)
#define GRID_C 1024               // total blocks (= 4 blocks/CU * 256 CU)
#define RPI    (GRID_C / SEGS)    // 64 rows in flight
#define FITERS (BATCHES / RPI)    // 4 sequential rows per block
#define FOLDC  (CPRC / 64)        // 64 chunks folded per scan lane
#define LSTR   36                 // padded LDS chunk stride (36 % 32 == 4 -> conflict-free b128)

__global__ __launch_bounds__(TPB, 4)
void fused_kernel(const float* __restrict__ x, const float* __restrict__ lvl,
                  float* __restrict__ out, float* __restrict__ ws,
                  int* __restrict__ cnt, int* __restrict__ flg)
{
    __shared__ float ob[TPB * LSTR];   // 36 KB output staging
    __shared__ int bc;                 // arrival-count broadcast

    const int tid = threadIdx.x;
    const int seg = blockIdx.x & (SEGS - 1);
    const int rg  = blockIdx.x >> 4;   // row group 0..63 (contiguous blocks per row)

    for (int it = 0; it < FITERS; ++it) {
        const int row = it * RPI + rg;

        float b0[3], na1[3], na2[3];
        compute_coeffs(lvl[row], b0, na1, na2);

        const int c = seg * TPB + tid;                  // chunk index within row
        const float* xc = x + (size_t)row * S_LEN + (size_t)c * CCH;
        float xm1 = 0.f, xm2 = 0.f;
        if (c > 0) { float2 t = *(const float2*)(xc - 2); xm2 = t.x; xm1 = t.y; }

        // x chunk -> registers (kept live through phase 3; read x from HBM ONCE)
        float4 buf[8];
        #pragma unroll
        for (int j = 0; j < 8; ++j) buf[j] = ((const float4*)xc)[j];

        float* wrow = ws + (size_t)row * (6 * CPRC);

        // -------- phase 1: zero-state response --------
        {
            float y1[3] = {0.f,0.f,0.f}, y2[3] = {0.f,0.f,0.f};
            float p1 = xm1, p2 = xm2, dummy;
            #pragma unroll
            for (int i = 0; i < 8; ++i) {
                float4 q = buf[i];
                STEP3(q.x, p2, dummy)
                STEP3(q.y, p1, dummy)
                STEP3(q.z, q.x, dummy)
                STEP3(q.w, q.y, dummy)
                p2 = q.z; p1 = q.w;
            }
            (void)dummy;
            // publish chunk-end states at device scope (write-through, no local cache allocate)
            agent_store(&wrow[0 * CPRC + c], y1[0]);
            agent_store(&wrow[1 * CPRC + c], y2[0]);
            agent_store(&wrow[2 * CPRC + c], y1[1]);
            agent_store(&wrow[3 * CPRC + c], y2[1]);
            agent_store(&wrow[4 * CPRC + c], y1[2]);
            agent_store(&wrow[5 * CPRC + c], y2[2]);
        }

        __syncthreads();   // drains all waves' vmcnt before counting the block as arrived
        if (tid == 0) {
            __threadfence();
            bc = __hip_atomic_fetch_add(&cnt[row], 1, __ATOMIC_ACQ_REL, __HIP_MEMORY_SCOPE_AGENT);
        }
        __syncthreads();
        const bool scanner = (bc == SEGS - 1);   // last arriver scans this row

        // -------- phase 2 (scanner block only): affine scan over 4096 chunk states --------
        if (scanner) {
            const int wv = tid >> 6, ln = tid & 63;
            if (wv < 3) {
                const float A1 = na1[wv], A2 = na2[wv];
                // homogeneous solution over one chunk -> H
                float hm1 = 1.f, hm2 = 0.f, hm3 = 0.f;
                for (int i = 0; i < CCH; ++i) {
                    float h = fmaf(A1, hm1, A2 * hm2);
                    hm3 = hm2; hm2 = hm1; hm1 = h;
                }
                const float H00 = hm1, H01 = A2 * hm2;
                const float H10 = hm2, H11 = A2 * hm3;

                float* z1p = wrow + (2 * wv) * CPRC;
                float* z2p = wrow + (2 * wv + 1) * CPRC;

                // fold this lane's 64 chunks (plain loads: first touch after acquire -> fresh, pipelined)
                float s1 = 0.f, s2 = 0.f;
                #pragma unroll 8
                for (int j = 0; j < FOLDC; ++j) {
                    int cc = ln * FOLDC + j;
                    float z1 = z1p[cc], z2 = z2p[cc];
                    float n1 = z1 + H00 * s1 + H01 * s2;
                    float n2 = z2 + H10 * s1 + H11 * s2;
                    s1 = n1; s2 = n2;
                }
                // A = H^64 via 6 squarings
                float P00 = H00, P01 = H01, P10 = H10, P11 = H11;
                #pragma unroll
                for (int t = 0; t < 6; ++t) {
                    float Q00 = P00 * P00 + P01 * P10;
                    float Q01 = P00 * P01 + P01 * P11;
                    float Q10 = P10 * P00 + P11 * P10;
                    float Q11 = P10 * P01 + P11 * P11;
                    P00 = Q00; P01 = Q01; P10 = Q10; P11 = Q11;
                }
                // Kogge-Stone inclusive scan of affine maps across 64 lanes
                float A00 = P00, A01 = P01, A10 = P10, A11 = P11, bb1 = s1, bb2 = s2;
                for (int d = 1; d < 64; d <<= 1) {
                    float iA00 = __shfl_up(A00, d), iA01 = __shfl_up(A01, d);
                    float iA10 = __shfl_up(A10, d), iA11 = __shfl_up(A11, d);
                    float ib1  = __shfl_up(bb1, d), ib2  = __shfl_up(bb2, d);
                    if (ln >= d) {
                        float nb1 = A00 * ib1 + A01 * ib2 + bb1;
                        float nb2 = A10 * ib1 + A11 * ib2 + bb2;
                        float n00 = A00 * iA00 + A01 * iA10;
                        float n01 = A00 * iA01 + A01 * iA11;
                        float n10 = A10 * iA00 + A11 * iA10;
                        float n11 = A10 * iA01 + A11 * iA11;
                        A00 = n00; A01 = n01; A10 = n10; A11 = n11;
                        bb1 = nb1; bb2 = nb2;
                    }
                }
                float e1 = __shfl_up(bb1, 1), e2 = __shfl_up(bb2, 1);
                if (ln == 0) { e1 = 0.f; e2 = 0.f; }

                // replay: overwrite zs with corrected chunk-ENTRY states (agent-visible)
                s1 = e1; s2 = e2;
                #pragma unroll 8
                for (int j = 0; j < FOLDC; ++j) {
                    int cc = ln * FOLDC + j;
                    float z1 = z1p[cc], z2 = z2p[cc];     // L2-hot from fold pass
                    agent_store(&z1p[cc], s1);
                    agent_store(&z2p[cc], s2);
                    float n1 = z1 + H00 * s1 + H01 * s2;
                    float n2 = z2 + H10 * s1 + H11 * s2;
                    s1 = n1; s2 = n2;
                }
            }
            __syncthreads();   // all scan waves done (vmcnt drained)
            if (tid == 0) {
                __threadfence();
                __hip_atomic_store(&flg[row], 1, __ATOMIC_RELEASE, __HIP_MEMORY_SCOPE_AGENT);
            }
        } else {
            if (tid == 0) {
                while (__hip_atomic_load(&flg[row], __ATOMIC_ACQUIRE, __HIP_MEMORY_SCOPE_AGENT) == 0)
                    __builtin_amdgcn_s_sleep(4);
            }
        }
        __syncthreads();   // whole block may now read corrected entry states

        // -------- phase 3: exact recurrence from register-held x, staged coalesced store --------
        {
            float y1[3], y2[3];
            y1[0] = agent_load(&wrow[0 * CPRC + c]); y2[0] = agent_load(&wrow[1 * CPRC + c]);
            y1[1] = agent_load(&wrow[2 * CPRC + c]); y2[1] = agent_load(&wrow[3 * CPRC + c]);
            y1[2] = agent_load(&wrow[4 * CPRC + c]); y2[2] = agent_load(&wrow[5 * CPRC + c]);

            float p1 = xm1, p2 = xm2;
            float* myob = ob + tid * LSTR;
            const float is3 = 0.57735026918962576f;   // 1/sqrt(3)
            #pragma unroll
            for (int i = 0; i < 8; ++i) {
                float4 q = buf[i];
                float4 o;
                STEP3(q.x, p2, o.x)
                STEP3(q.y, p1, o.y)
                STEP3(q.z, q.x, o.z)
                STEP3(q.w, q.y, o.w)
                p2 = q.z; p1 = q.w;
                o.x *= is3; o.y *= is3; o.z *= is3; o.w *= is3;
                *(float4*)(myob + 4 * i) = o;        // b128 write, conflict-free (stride 36)
            }
            __syncthreads();
            // cooperative coalesced store of the block's 8192-sample segment
            float4* obase = (float4*)(out + (size_t)row * S_LEN + (size_t)seg * (TPB * CCH));
            #pragma unroll
            for (int j = 0; j < 8; ++j) {
                int f   = j * TPB + tid;
                int ch  = f >> 3;            // 8 float4 per chunk
                int off = (f & 7) * 4;
                obase[f] = *(const float4*)(ob + ch * LSTR + off);
            }
            __syncthreads();   // guard LDS reuse by next iteration
        }
    }
}

// ================= fallback 3-kernel path (round-3 code) =================

template<int CHUNK>
__global__ __launch_bounds__(256)
void k1_zerostate(const float* __restrict__ x, const float* __restrict__ level_arr,
                  float* __restrict__ ws)
{
    constexpr int CPR = S_LEN / CHUNK;
    constexpr int NV  = CHUNK / 4;
    const int g   = blockIdx.x * 256 + threadIdx.x;
    const int row = g / CPR;
    const int c   = g & (CPR - 1);

    float b0[3], na1[3], na2[3];
    compute_coeffs(level_arr[row], b0, na1, na2);

    const float* xc = x + (size_t)row * S_LEN + (size_t)c * CHUNK;
    float xm1 = 0.f, xm2 = 0.f;
    if (c > 0) { float2 t = *(const float2*)(xc - 2); xm2 = t.x; xm1 = t.y; }

    float y1[3] = {0.f,0.f,0.f}, y2[3] = {0.f,0.f,0.f};
    const float4* xv = (const float4*)xc;
    float4 buf[4];
    #pragma unroll
    for (int j = 0; j < 4; ++j) buf[j] = xv[j];
    float dummy;
    #pragma unroll
    for (int i = 0; i < NV; ++i) {
        float4 q = buf[i & 3];
        if (i + 4 < NV) buf[i & 3] = xv[i + 4];
        STEP3(q.x, xm2, dummy)
        STEP3(q.y, xm1, dummy)
        STEP3(q.z, q.x, dummy)
        STEP3(q.w, q.y, dummy)
        xm2 = q.z; xm1 = q.w;
    }
    (void)dummy;

    float* wrow = ws + (size_t)row * 6 * CPR;
    wrow[0 * CPR + c] = y1[0]; wrow[1 * CPR + c] = y2[0];
    wrow[2 * CPR + c] = y1[1]; wrow[3 * CPR + c] = y2[1];
    wrow[4 * CPR + c] = y1[2]; wrow[5 * CPR + c] = y2[2];
}

template<int CHUNK>
__global__ __launch_bounds__(192)
void k2_scan(const float* __restrict__ level_arr, float* __restrict__ ws)
{
    constexpr int CPR  = S_LEN / CHUNK;
    constexpr int FOLD = CPR / 64;
    constexpr int LSTRK = CPR + CPR / 32;
    __shared__ float st[6 * LSTRK];

    const int row  = blockIdx.x;
    const int wave = threadIdx.x >> 6;
    const int lane = threadIdx.x & 63;

    float b0[3], na1[3], na2[3];
    compute_coeffs(level_arr[row], b0, na1, na2);
    const float A1 = (wave == 0) ? na1[0] : ((wave == 1) ? na1[1] : na1[2]);
    const float A2 = (wave == 0) ? na2[0] : ((wave == 1) ? na2[1] : na2[2]);

    float* wrow = ws + (size_t)row * 6 * CPR;

    #pragma unroll
    for (int e = 2 * wave; e <= 2 * wave + 1; ++e)
        for (int i = lane; i < CPR; i += 64)
            st[e * LSTRK + i + (i >> 5)] = wrow[e * CPR + i];
    __syncthreads();

    float hm1 = 1.f, hm2 = 0.f, hm3 = 0.f;
    for (int i = 0; i < CHUNK; ++i) {
        float h = fmaf(A1, hm1, A2 * hm2);
        hm3 = hm2; hm2 = hm1; hm1 = h;
    }
    const float H00 = hm1, H01 = A2 * hm2;
    const float H10 = hm2, H11 = A2 * hm3;

    float* z1p = st + (2 * wave) * LSTRK;
    float* z2p = st + (2 * wave + 1) * LSTRK;

    float s1 = 0.f, s2 = 0.f;
    #pragma unroll
    for (int j = 0; j < FOLD; ++j) {
        int cc = lane * FOLD + j, ca = cc + (cc >> 5);
        float z1 = z1p[ca], z2 = z2p[ca];
        float n1 = z1 + H00 * s1 + H01 * s2;
        float n2 = z2 + H10 * s1 + H11 * s2;
        s1 = n1; s2 = n2;
    }
    float P00 = H00, P01 = H01, P10 = H10, P11 = H11;
    #pragma unroll
    for (int t = 0; (1 << t) < FOLD; ++t) {
        float Q00 = P00 * P00 + P01 * P10;
        float Q01 = P00 * P01 + P01 * P11;
        float Q10 = P10 * P00 + P11 * P10;
        float Q11 = P10 * P01 + P11 * P11;
        P00 = Q00; P01 = Q01; P10 = Q10; P11 = Q11;
    }
    float A00 = P00, A01 = P01, A10 = P10, A11 = P11, bb1 = s1, bb2 = s2;
    for (int d = 1; d < 64; d <<= 1) {
        float iA00 = __shfl_up(A00, d), iA01 = __shfl_up(A01, d);
        float iA10 = __shfl_up(A10, d), iA11 = __shfl_up(A11, d);
        float ib1  = __shfl_up(bb1, d), ib2  = __shfl_up(bb2, d);
        if (lane >= d) {
            float nb1 = A00 * ib1 + A01 * ib2 + bb1;
            float nb2 = A10 * ib1 + A11 * ib2 + bb2;
            float n00 = A00 * iA00 + A01 * iA10;
            float n01 = A00 * iA01 + A01 * iA11;
            float n10 = A10 * iA00 + A11 * iA10;
            float n11 = A10 * iA01 + A11 * iA11;
            A00 = n00; A01 = n01; A10 = n10; A11 = n11;
            bb1 = nb1; bb2 = nb2;
        }
    }
    float e1 = __shfl_up(bb1, 1), e2 = __shfl_up(bb2, 1);
    if (lane == 0) { e1 = 0.f; e2 = 0.f; }

    s1 = e1; s2 = e2;
    #pragma unroll
    for (int j = 0; j < FOLD; ++j) {
        int cc = lane * FOLD + j, ca = cc + (cc >> 5);
        float z1 = z1p[ca], z2 = z2p[ca];
        z1p[ca] = s1; z2p[ca] = s2;
        float n1 = z1 + H00 * s1 + H01 * s2;
        float n2 = z2 + H10 * s1 + H11 * s2;
        s1 = n1; s2 = n2;
    }
    __syncthreads();

    #pragma unroll
    for (int e = 2 * wave; e <= 2 * wave + 1; ++e)
        for (int i = lane; i < CPR; i += 64)
            wrow[e * CPR + i] = st[e * LSTRK + i + (i >> 5)];
}

__global__ __launch_bounds__(256)
void k3_apply_staged(const float* __restrict__ x, const float* __restrict__ level_arr,
                     const float* __restrict__ ws, float* __restrict__ out)
{
    constexpr int CHUNK = 64;
    constexpr int CPR   = S_LEN / CHUNK;
    constexpr int TPB3  = 256;
    constexpr int BPR   = CPR / TPB3;
    constexpr int NV    = CHUNK / 4;
    constexpr int LSTR3 = CHUNK + 1;
    __shared__ float ob[TPB3 * LSTR3];

    const int tid = threadIdx.x;
    const int row = blockIdx.x / BPR;
    const int seg = blockIdx.x % BPR;
    const int c   = seg * TPB3 + tid;

    float b0[3], na1[3], na2[3];
    compute_coeffs(level_arr[row], b0, na1, na2);

    const float* wrow = ws + (size_t)row * 6 * CPR;
    float y1[3], y2[3];
    y1[0] = wrow[0 * CPR + c]; y2[0] = wrow[1 * CPR + c];
    y1[1] = wrow[2 * CPR + c]; y2[1] = wrow[3 * CPR + c];
    y1[2] = wrow[4 * CPR + c]; y2[2] = wrow[5 * CPR + c];

    const float* xc = x + (size_t)row * S_LEN + (size_t)c * CHUNK;
    float xm1 = 0.f, xm2 = 0.f;
    if (c > 0) { float2 t = *(const float2*)(xc - 2); xm2 = t.x; xm1 = t.y; }

    const float4* xv = (const float4*)xc;
    const float inv_sqrt_nb = 0.57735026918962576f;
    float* myob = ob + tid * LSTR3;

    float4 buf[4];
    #pragma unroll
    for (int j = 0; j < 4; ++j) buf[j] = xv[j];
    #pragma unroll
    for (int i = 0; i < NV; ++i) {
        float4 q = buf[i & 3];
        if (i + 4 < NV) buf[i & 3] = xv[i + 4];
        float4 o;
        STEP3(q.x, xm2, o.x)
        STEP3(q.y, xm1, o.y)
        STEP3(q.z, q.x, o.z)
        STEP3(q.w, q.y, o.w)
        xm2 = q.z; xm1 = q.w;
        myob[4 * i + 0] = o.x * inv_sqrt_nb;
        myob[4 * i + 1] = o.y * inv_sqrt_nb;
        myob[4 * i + 2] = o.z * inv_sqrt_nb;
        myob[4 * i + 3] = o.w * inv_sqrt_nb;
    }
    __syncthreads();

    float4* obase = (float4*)(out + (size_t)row * S_LEN + (size_t)seg * (TPB3 * CHUNK));
    #pragma unroll
    for (int j = 0; j < NV; ++j) {
        int f = j * TPB3 + tid;
        int i = f * 4;
        int ch = i >> 6, off = i & 63;
        const float* p = ob + ch * LSTR3 + off;
        float4 o = { p[0], p[1], p[2], p[3] };
        obase[f] = o;
    }
}

// ================= launch =================

extern "C" void kernel_launch(void* const* d_in, const int* in_sizes, int n_in,
                              void* d_out, int out_size, void* d_ws, size_t ws_size,
                              hipStream_t stream) {
    const float* audio = (const float*)d_in[0];
    const float* level = (const float*)d_in[1];
    float* out = (float*)d_out;
    float* ws  = (float*)d_ws;
    (void)in_sizes; (void)n_in; (void)out_size;

    const size_t state_bytes = (size_t)BATCHES * 6 * CPRC * sizeof(float);  // 25.17 MB
    const size_t need_fused  = state_bytes + 2 * BATCHES * sizeof(int);

    int occ = 0;
    hipError_t oe = hipOccupancyMaxActiveBlocksPerMultiprocessor(&occ, fused_kernel, TPB, 0);
    const bool can_fused = (oe == hipSuccess) && (occ >= 4) && (ws_size >= need_fused);

    if (can_fused) {
        int* cnt = (int*)((char*)d_ws + state_bytes);
        int* flg = cnt + BATCHES;
        hipMemsetAsync(cnt, 0, 2 * BATCHES * sizeof(int), stream);
        fused_kernel<<<GRID_C, TPB, 0, stream>>>(audio, level, out, ws, cnt, flg);
    } else {
        constexpr int CHUNK = 64;
        constexpr int CPR = S_LEN / CHUNK;
        const int total_threads = BATCHES * CPR;
        k1_zerostate<CHUNK><<<total_threads / 256, 256, 0, stream>>>(audio, level, ws);
        k2_scan<CHUNK><<<BATCHES, 192, 0, stream>>>(level, ws);
        k3_apply_staged<<<total_threads / 256, 256, 0, stream>>>(audio, level, ws, out);
    }
}

// Round 5
// 98.471 us; speedup vs baseline: 1.0040x; 1.0040x over previous
//
#include <hip/hip_runtime.h>
#include <hip/hip_cooperative_groups.h>
#include <math.h>

#ifndef M_PI
#define M_PI 3.14159265358979323846
#endif

#define BATCHES 256
#define S_LEN   131072

namespace cg = cooperative_groups;

// ---------------- shared helpers ----------------

__device__ __forceinline__ void compute_coeffs(float level_in, float b0[3], float na1[3], float na2[3]) {
    const float FD[3] = {270.0f, 800.0f, 2300.0f};
    const float FN[3] = {500.0f, 1500.0f, 2500.0f};
    const float FB[3] = {730.0f, 2100.0f, 3000.0f};
    float level = fminf(fmaxf(level_in, 0.0f), 1.0f);
    float t_low  = fminf(fmaxf(level * 2.0f, 0.0f), 1.0f);
    float t_high = fminf(fmaxf((level - 0.5f) * 2.0f, 0.0f), 1.0f);
    bool hi = (level >= 0.5f);
    const float W0 = (float)(2.0 * M_PI / 16000.0);
    #pragma unroll
    for (int k = 0; k < 3; ++k) {
        float f, q;
        if (hi) { f = (1.0f - t_high) * FN[k] + t_high * FB[k];
                  q = (1.0f - t_high) * 8.0f  + t_high * 12.0f; }
        else    { f = (1.0f - t_low) * FD[k] + t_low * FN[k];
                  q = (1.0f - t_low) * 5.0f  + t_low * 8.0f; }
        float omega = W0 * f;
        float sn = sinf(omega), cs = cosf(omega);
        float alpha = sn / (2.0f * fmaxf(q, 0.5f));
        float a0 = 1.0f + alpha;
        b0[k]  = alpha / a0;             // b2 == -b0 exactly
        na1[k] = (2.0f * cs) / a0;       // -a1
        na2[k] = -((1.0f - alpha) / a0); // -a2
    }
}

#define STEP3(XT, XTM2, SUMV)                                                    \
    {                                                                            \
        float d = (XT) - (XTM2);                                                 \
        float e0 = fmaf(b0[0], d, na2[0] * y2[0]);                               \
        float e1 = fmaf(b0[1], d, na2[1] * y2[1]);                               \
        float e2 = fmaf(b0[2], d, na2[2] * y2[2]);                               \
        float yy0 = fmaf(na1[0], y1[0], e0);                                     \
        float yy1 = fmaf(na1[1], y1[1], e1);                                     \
        float yy2 = fmaf(na1[2], y1[2], e2);                                     \
        y2[0] = y1[0]; y1[0] = yy0;                                              \
        y2[1] = y1[1]; y1[1] = yy1;                                              \
        y2[2] = y1[2]; y1[2] = yy2;                                              \
        SUMV = (yy0 + yy1 + yy2);                                                \
    }

// ================= cooperative single-kernel path =================
// CCH=64 samples/thread held in 16 float4 registers across both passes.
// 1024 blocks x 256 thr (4 blocks/CU via 33.8KB LDS), 2 rounds of 128 rows:
//   p1(zero-state) -> grid.sync -> p2(128 parallel row-scans) -> grid.sync -> p3

#define TPB2   256
#define CCH2   64
#define CPR2   (S_LEN / CCH2)     // 2048 chunks per row
#define SEGS2  (CPR2 / TPB2)      // 8 blocks per row
#define GRID2  1024
#define ROWSRD (GRID2 / SEGS2)    // 128 rows per round
#define ROUNDS (BATCHES / ROWSRD) // 2
#define FOLD2  (CPR2 / 64)        // 32 chunks folded per scan lane
#define LSTR2  33                 // odd stride -> conflict-free scalar LDS

__global__ __launch_bounds__(TPB2, 4)
void coop_kernel(const float* __restrict__ x, const float* __restrict__ lvl,
                 float* __restrict__ out, float* __restrict__ ws)
{
    cg::grid_group grid = cg::this_grid();
    __shared__ float ob[TPB2 * LSTR2];   // 33.8 KB output staging

    const int tid = threadIdx.x;
    const int bid = blockIdx.x;
    const int seg = bid & (SEGS2 - 1);
    const int rg  = bid >> 3;            // 0..127: row group within round

    for (int rd = 0; rd < ROUNDS; ++rd) {
        const int row = rd * ROWSRD + rg;

        float b0[3], na1[3], na2[3];
        compute_coeffs(lvl[row], b0, na1, na2);

        const int c = seg * TPB2 + tid;                 // chunk index within row
        const float* xc = x + (size_t)row * S_LEN + (size_t)c * CCH2;
        float xm1 = 0.f, xm2 = 0.f;
        if (c > 0) { float2 t = *(const float2*)(xc - 2); xm2 = t.x; xm1 = t.y; }

        // x chunk -> registers (64 VGPR), single HBM read of x
        float4 buf[16];
        #pragma unroll
        for (int j = 0; j < 16; ++j) buf[j] = ((const float4*)xc)[j];

        float* wrow = ws + (size_t)row * 6 * CPR2;

        // -------- phase 1: zero-state response --------
        {
            float y1[3] = {0.f,0.f,0.f}, y2[3] = {0.f,0.f,0.f};
            float p1 = xm1, p2 = xm2, dummy;
            #pragma unroll
            for (int i = 0; i < 16; ++i) {
                float4 q = buf[i];
                STEP3(q.x, p2, dummy)
                STEP3(q.y, p1, dummy)
                STEP3(q.z, q.x, dummy)
                STEP3(q.w, q.y, dummy)
                p2 = q.z; p1 = q.w;
            }
            (void)dummy;
            wrow[0 * CPR2 + c] = y1[0]; wrow[1 * CPR2 + c] = y2[0];
            wrow[2 * CPR2 + c] = y1[1]; wrow[3 * CPR2 + c] = y2[1];
            wrow[4 * CPR2 + c] = y1[2]; wrow[5 * CPR2 + c] = y2[2];
        }

        grid.sync();

        // -------- phase 2: blocks 0..127 each scan one row (no convoy) --------
        if (bid < ROWSRD) {
            const int srow = rd * ROWSRD + bid;
            const int wv = tid >> 6, ln = tid & 63;
            if (wv < 3) {
                float sb0[3], sa1[3], sa2[3];
                compute_coeffs(lvl[srow], sb0, sa1, sa2);
                const float A1 = sa1[wv], A2 = sa2[wv];

                // homogeneous solution over one chunk -> H
                float hm1 = 1.f, hm2 = 0.f, hm3 = 0.f;
                for (int i = 0; i < CCH2; ++i) {
                    float h = fmaf(A1, hm1, A2 * hm2);
                    hm3 = hm2; hm2 = hm1; hm1 = h;
                }
                const float H00 = hm1, H01 = A2 * hm2;
                const float H10 = hm2, H11 = A2 * hm3;

                float* srw = ws + (size_t)srow * 6 * CPR2;
                float* z1p = srw + (2 * wv) * CPR2;
                float* z2p = srw + (2 * wv + 1) * CPR2;

                // fold this lane's 32 chunks
                float s1 = 0.f, s2 = 0.f;
                #pragma unroll 8
                for (int j = 0; j < FOLD2; ++j) {
                    int cc = ln * FOLD2 + j;
                    float z1 = z1p[cc], z2 = z2p[cc];
                    float n1 = z1 + H00 * s1 + H01 * s2;
                    float n2 = z2 + H10 * s1 + H11 * s2;
                    s1 = n1; s2 = n2;
                }
                // A = H^32 via 5 squarings
                float P00 = H00, P01 = H01, P10 = H10, P11 = H11;
                #pragma unroll
                for (int t = 0; t < 5; ++t) {
                    float Q00 = P00 * P00 + P01 * P10;
                    float Q01 = P00 * P01 + P01 * P11;
                    float Q10 = P10 * P00 + P11 * P10;
                    float Q11 = P10 * P01 + P11 * P11;
                    P00 = Q00; P01 = Q01; P10 = Q10; P11 = Q11;
                }
                // Kogge-Stone inclusive scan of affine maps across 64 lanes
                float A00 = P00, A01 = P01, A10 = P10, A11 = P11, bb1 = s1, bb2 = s2;
                for (int d = 1; d < 64; d <<= 1) {
                    float iA00 = __shfl_up(A00, d), iA01 = __shfl_up(A01, d);
                    float iA10 = __shfl_up(A10, d), iA11 = __shfl_up(A11, d);
                    float ib1  = __shfl_up(bb1, d), ib2  = __shfl_up(bb2, d);
                    if (ln >= d) {
                        float nb1 = A00 * ib1 + A01 * ib2 + bb1;
                        float nb2 = A10 * ib1 + A11 * ib2 + bb2;
                        float n00 = A00 * iA00 + A01 * iA10;
                        float n01 = A00 * iA01 + A01 * iA11;
                        float n10 = A10 * iA00 + A11 * iA10;
                        float n11 = A10 * iA01 + A11 * iA11;
                        A00 = n00; A01 = n01; A10 = n10; A11 = n11;
                        bb1 = nb1; bb2 = nb2;
                    }
                }
                float e1 = __shfl_up(bb1, 1), e2 = __shfl_up(bb2, 1);
                if (ln == 0) { e1 = 0.f; e2 = 0.f; }

                // replay: overwrite zs with corrected chunk-ENTRY states
                s1 = e1; s2 = e2;
                #pragma unroll 8
                for (int j = 0; j < FOLD2; ++j) {
                    int cc = ln * FOLD2 + j;
                    float z1 = z1p[cc], z2 = z2p[cc];
                    z1p[cc] = s1; z2p[cc] = s2;
                    float n1 = z1 + H00 * s1 + H01 * s2;
                    float n2 = z2 + H10 * s1 + H11 * s2;
                    s1 = n1; s2 = n2;
                }
            }
        }

        grid.sync();

        // -------- phase 3: exact recurrence from register-held x --------
        {
            float y1[3], y2[3];
            y1[0] = wrow[0 * CPR2 + c]; y2[0] = wrow[1 * CPR2 + c];
            y1[1] = wrow[2 * CPR2 + c]; y2[1] = wrow[3 * CPR2 + c];
            y1[2] = wrow[4 * CPR2 + c]; y2[2] = wrow[5 * CPR2 + c];

            float p1 = xm1, p2 = xm2;
            float* myob = ob + tid * LSTR2;
            const float is3 = 0.57735026918962576f;   // 1/sqrt(3)
            float4* obase = (float4*)(out + (size_t)row * S_LEN + (size_t)seg * (TPB2 * CCH2));

            #pragma unroll
            for (int half = 0; half < 2; ++half) {
                #pragma unroll
                for (int i = 0; i < 8; ++i) {
                    float4 q = buf[half * 8 + i];
                    float4 o;
                    STEP3(q.x, p2, o.x)
                    STEP3(q.y, p1, o.y)
                    STEP3(q.z, q.x, o.z)
                    STEP3(q.w, q.y, o.w)
                    p2 = q.z; p1 = q.w;
                    // scalar LDS writes, bank=(t+4i+k)%32 -> 2-way max (free)
                    myob[4 * i + 0] = o.x * is3;
                    myob[4 * i + 1] = o.y * is3;
                    myob[4 * i + 2] = o.z * is3;
                    myob[4 * i + 3] = o.w * is3;
                }
                __syncthreads();
                // cooperative coalesced store of this half (32 samples of each chunk)
                #pragma unroll
                for (int j = 0; j < 8; ++j) {
                    int f   = j * TPB2 + tid;
                    int ch  = f >> 3;              // local chunk
                    int off = (f & 7) * 4;         // float offset within half
                    const float* p = ob + ch * LSTR2 + off;
                    float4 o = { p[0], p[1], p[2], p[3] };
                    obase[(size_t)ch * 16 + half * 8 + (f & 7)] = o;
                }
                __syncthreads();   // protect LDS before next half / next round
            }
        }
    }
}

// ================= fallback 3-kernel path (round-3 code, known-good) =================

template<int CHUNK>
__global__ __launch_bounds__(256)
void k1_zerostate(const float* __restrict__ x, const float* __restrict__ level_arr,
                  float* __restrict__ ws)
{
    constexpr int CPR = S_LEN / CHUNK;
    constexpr int NV  = CHUNK / 4;
    const int g   = blockIdx.x * 256 + threadIdx.x;
    const int row = g / CPR;
    const int c   = g & (CPR - 1);

    float b0[3], na1[3], na2[3];
    compute_coeffs(level_arr[row], b0, na1, na2);

    const float* xc = x + (size_t)row * S_LEN + (size_t)c * CHUNK;
    float xm1 = 0.f, xm2 = 0.f;
    if (c > 0) { float2 t = *(const float2*)(xc - 2); xm2 = t.x; xm1 = t.y; }

    float y1[3] = {0.f,0.f,0.f}, y2[3] = {0.f,0.f,0.f};
    const float4* xv = (const float4*)xc;
    float4 buf[4];
    #pragma unroll
    for (int j = 0; j < 4; ++j) buf[j] = xv[j];
    float dummy;
    #pragma unroll
    for (int i = 0; i < NV; ++i) {
        float4 q = buf[i & 3];
        if (i + 4 < NV) buf[i & 3] = xv[i + 4];
        STEP3(q.x, xm2, dummy)
        STEP3(q.y, xm1, dummy)
        STEP3(q.z, q.x, dummy)
        STEP3(q.w, q.y, dummy)
        xm2 = q.z; xm1 = q.w;
    }
    (void)dummy;

    float* wrow = ws + (size_t)row * 6 * CPR;
    wrow[0 * CPR + c] = y1[0]; wrow[1 * CPR + c] = y2[0];
    wrow[2 * CPR + c] = y1[1]; wrow[3 * CPR + c] = y2[1];
    wrow[4 * CPR + c] = y1[2]; wrow[5 * CPR + c] = y2[2];
}

template<int CHUNK>
__global__ __launch_bounds__(192)
void k2_scan(const float* __restrict__ level_arr, float* __restrict__ ws)
{
    constexpr int CPR  = S_LEN / CHUNK;
    constexpr int FOLD = CPR / 64;
    constexpr int LSTRK = CPR + CPR / 32;
    __shared__ float st[6 * LSTRK];

    const int row  = blockIdx.x;
    const int wave = threadIdx.x >> 6;
    const int lane = threadIdx.x & 63;

    float b0[3], na1[3], na2[3];
    compute_coeffs(level_arr[row], b0, na1, na2);
    const float A1 = (wave == 0) ? na1[0] : ((wave == 1) ? na1[1] : na1[2]);
    const float A2 = (wave == 0) ? na2[0] : ((wave == 1) ? na2[1] : na2[2]);

    float* wrow = ws + (size_t)row * 6 * CPR;

    #pragma unroll
    for (int e = 2 * wave; e <= 2 * wave + 1; ++e)
        for (int i = lane; i < CPR; i += 64)
            st[e * LSTRK + i + (i >> 5)] = wrow[e * CPR + i];
    __syncthreads();

    float hm1 = 1.f, hm2 = 0.f, hm3 = 0.f;
    for (int i = 0; i < CHUNK; ++i) {
        float h = fmaf(A1, hm1, A2 * hm2);
        hm3 = hm2; hm2 = hm1; hm1 = h;
    }
    const float H00 = hm1, H01 = A2 * hm2;
    const float H10 = hm2, H11 = A2 * hm3;

    float* z1p = st + (2 * wave) * LSTRK;
    float* z2p = st + (2 * wave + 1) * LSTRK;

    float s1 = 0.f, s2 = 0.f;
    #pragma unroll
    for (int j = 0; j < FOLD; ++j) {
        int cc = lane * FOLD + j, ca = cc + (cc >> 5);
        float z1 = z1p[ca], z2 = z2p[ca];
        float n1 = z1 + H00 * s1 + H01 * s2;
        float n2 = z2 + H10 * s1 + H11 * s2;
        s1 = n1; s2 = n2;
    }
    float P00 = H00, P01 = H01, P10 = H10, P11 = H11;
    #pragma unroll
    for (int t = 0; (1 << t) < FOLD; ++t) {
        float Q00 = P00 * P00 + P01 * P10;
        float Q01 = P00 * P01 + P01 * P11;
        float Q10 = P10 * P00 + P11 * P10;
        float Q11 = P10 * P01 + P11 * P11;
        P00 = Q00; P01 = Q01; P10 = Q10; P11 = Q11;
    }
    float A00 = P00, A01 = P01, A10 = P10, A11 = P11, bb1 = s1, bb2 = s2;
    for (int d = 1; d < 64; d <<= 1) {
        float iA00 = __shfl_up(A00, d), iA01 = __shfl_up(A01, d);
        float iA10 = __shfl_up(A10, d), iA11 = __shfl_up(A11, d);
        float ib1  = __shfl_up(bb1, d), ib2  = __shfl_up(bb2, d);
        if (lane >= d) {
            float nb1 = A00 * ib1 + A01 * ib2 + bb1;
            float nb2 = A10 * ib1 + A11 * ib2 + bb2;
            float n00 = A00 * iA00 + A01 * iA10;
            float n01 = A00 * iA01 + A01 * iA11;
            float n10 = A10 * iA00 + A11 * iA10;
            float n11 = A10 * iA01 + A11 * iA11;
            A00 = n00; A01 = n01; A10 = n10; A11 = n11;
            bb1 = nb1; bb2 = nb2;
        }
    }
    float e1 = __shfl_up(bb1, 1), e2 = __shfl_up(bb2, 1);
    if (lane == 0) { e1 = 0.f; e2 = 0.f; }

    s1 = e1; s2 = e2;
    #pragma unroll
    for (int j = 0; j < FOLD; ++j) {
        int cc = lane * FOLD + j, ca = cc + (cc >> 5);
        float z1 = z1p[ca], z2 = z2p[ca];
        z1p[ca] = s1; z2p[ca] = s2;
        float n1 = z1 + H00 * s1 + H01 * s2;
        float n2 = z2 + H10 * s1 + H11 * s2;
        s1 = n1; s2 = n2;
    }
    __syncthreads();

    #pragma unroll
    for (int e = 2 * wave; e <= 2 * wave + 1; ++e)
        for (int i = lane; i < CPR; i += 64)
            wrow[e * CPR + i] = st[e * LSTRK + i + (i >> 5)];
}

__global__ __launch_bounds__(256)
void k3_apply_staged(const float* __restrict__ x, const float* __restrict__ level_arr,
                     const float* __restrict__ ws, float* __restrict__ out)
{
    constexpr int CHUNK = 64;
    constexpr int CPR   = S_LEN / CHUNK;
    constexpr int TPB3  = 256;
    constexpr int BPR   = CPR / TPB3;
    constexpr int NV    = CHUNK / 4;
    constexpr int LSTR3 = CHUNK + 1;
    __shared__ float ob[TPB3 * LSTR3];

    const int tid = threadIdx.x;
    const int row = blockIdx.x / BPR;
    const int seg = blockIdx.x % BPR;
    const int c   = seg * TPB3 + tid;

    float b0[3], na1[3], na2[3];
    compute_coeffs(level_arr[row], b0, na1, na2);

    const float* wrow = ws + (size_t)row * 6 * CPR;
    float y1[3], y2[3];
    y1[0] = wrow[0 * CPR + c]; y2[0] = wrow[1 * CPR + c];
    y1[1] = wrow[2 * CPR + c]; y2[1] = wrow[3 * CPR + c];
    y1[2] = wrow[4 * CPR + c]; y2[2] = wrow[5 * CPR + c];

    const float* xc = x + (size_t)row * S_LEN + (size_t)c * CHUNK;
    float xm1 = 0.f, xm2 = 0.f;
    if (c > 0) { float2 t = *(const float2*)(xc - 2); xm2 = t.x; xm1 = t.y; }

    const float4* xv = (const float4*)xc;
    const float inv_sqrt_nb = 0.57735026918962576f;
    float* myob = ob + tid * LSTR3;

    float4 buf[4];
    #pragma unroll
    for (int j = 0; j < 4; ++j) buf[j] = xv[j];
    #pragma unroll
    for (int i = 0; i < NV; ++i) {
        float4 q = buf[i & 3];
        if (i + 4 < NV) buf[i & 3] = xv[i + 4];
        float4 o;
        STEP3(q.x, xm2, o.x)
        STEP3(q.y, xm1, o.y)
        STEP3(q.z, q.x, o.z)
        STEP3(q.w, q.y, o.w)
        xm2 = q.z; xm1 = q.w;
        myob[4 * i + 0] = o.x * inv_sqrt_nb;
        myob[4 * i + 1] = o.y * inv_sqrt_nb;
        myob[4 * i + 2] = o.z * inv_sqrt_nb;
        myob[4 * i + 3] = o.w * inv_sqrt_nb;
    }
    __syncthreads();

    float4* obase = (float4*)(out + (size_t)row * S_LEN + (size_t)seg * (TPB3 * CHUNK));
    #pragma unroll
    for (int j = 0; j < NV; ++j) {
        int f = j * TPB3 + tid;
        int i = f * 4;
        int ch = i >> 6, off = i & 63;
        const float* p = ob + ch * LSTR3 + off;
        float4 o = { p[0], p[1], p[2], p[3] };
        obase[f] = o;
    }
}

static void launch_fallback(const float* audio, const float* level, float* out,
                            float* ws, hipStream_t stream)
{
    constexpr int CHUNK = 64;
    constexpr int CPR = S_LEN / CHUNK;
    const int total_threads = BATCHES * CPR;
    k1_zerostate<CHUNK><<<total_threads / 256, 256, 0, stream>>>(audio, level, ws);
    k2_scan<CHUNK><<<BATCHES, 192, 0, stream>>>(level, ws);
    k3_apply_staged<<<total_threads / 256, 256, 0, stream>>>(audio, level, ws, out);
}

// ================= launch =================

extern "C" void kernel_launch(void* const* d_in, const int* in_sizes, int n_in,
                              void* d_out, int out_size, void* d_ws, size_t ws_size,
                              hipStream_t stream) {
    const float* audio = (const float*)d_in[0];
    const float* level = (const float*)d_in[1];
    float* out = (float*)d_out;
    float* ws  = (float*)d_ws;
    (void)in_sizes; (void)n_in; (void)out_size;

    const size_t need = (size_t)BATCHES * 6 * CPR2 * sizeof(float);  // 12.6 MB

    int dev = 0;
    hipGetDevice(&dev);
    int coop = 0;
    hipDeviceGetAttribute(&coop, hipDeviceAttributeCooperativeLaunch, dev);
    int occ = 0;
    hipError_t oe = hipOccupancyMaxActiveBlocksPerMultiprocessor(&occ, coop_kernel, TPB2, 0);

    bool launched = false;
    if (coop && oe == hipSuccess && occ >= 4 && ws_size >= need) {
        void* args[] = { (void*)&audio, (void*)&level, (void*)&out, (void*)&ws };
        hipError_t le = hipLaunchCooperativeKernel((const void*)coop_kernel,
                                                   dim3(GRID2), dim3(TPB2),
                                                   args, 0, stream);
        launched = (le == hipSuccess);
    }
    if (!launched)
        launch_fallback(audio, level, out, ws, stream);
}

// Round 6
// 98.006 us; speedup vs baseline: 1.0088x; 1.0047x over previous
//
#include <hip/hip_runtime.h>
#include <hip/hip_cooperative_groups.h>
#include <math.h>

#ifndef M_PI
#define M_PI 3.14159265358979323846
#endif

#define BATCHES 256
#define S_LEN   131072

namespace cg = cooperative_groups;

// ---------------- shared helpers ----------------

__device__ __forceinline__ void compute_coeffs(float level_in, float b0[3], float na1[3], float na2[3]) {
    const float FD[3] = {270.0f, 800.0f, 2300.0f};
    const float FN[3] = {500.0f, 1500.0f, 2500.0f};
    const float FB[3] = {730.0f, 2100.0f, 3000.0f};
    float level = fminf(fmaxf(level_in, 0.0f), 1.0f);
    float t_low  = fminf(fmaxf(level * 2.0f, 0.0f), 1.0f);
    float t_high = fminf(fmaxf((level - 0.5f) * 2.0f, 0.0f), 1.0f);
    bool hi = (level >= 0.5f);
    const float W0 = (float)(2.0 * M_PI / 16000.0);
    #pragma unroll
    for (int k = 0; k < 3; ++k) {
        float f, q;
        if (hi) { f = (1.0f - t_high) * FN[k] + t_high * FB[k];
                  q = (1.0f - t_high) * 8.0f  + t_high * 12.0f; }
        else    { f = (1.0f - t_low) * FD[k] + t_low * FN[k];
                  q = (1.0f - t_low) * 5.0f  + t_low * 8.0f; }
        float omega = W0 * f;
        float sn = sinf(omega), cs = cosf(omega);
        float alpha = sn / (2.0f * fmaxf(q, 0.5f));
        float a0 = 1.0f + alpha;
        b0[k]  = alpha / a0;             // b2 == -b0 exactly
        na1[k] = (2.0f * cs) / a0;       // -a1
        na2[k] = -((1.0f - alpha) / a0); // -a2
    }
}

#define STEP3(XT, XTM2, SUMV)                                                    \
    {                                                                            \
        float d = (XT) - (XTM2);                                                 \
        float e0 = fmaf(b0[0], d, na2[0] * y2[0]);                               \
        float e1 = fmaf(b0[1], d, na2[1] * y2[1]);                               \
        float e2 = fmaf(b0[2], d, na2[2] * y2[2]);                               \
        float yy0 = fmaf(na1[0], y1[0], e0);                                     \
        float yy1 = fmaf(na1[1], y1[1], e1);                                     \
        float yy2 = fmaf(na1[2], y1[2], e2);                                     \
        y2[0] = y1[0]; y1[0] = yy0;                                              \
        y2[1] = y1[1]; y1[1] = yy1;                                              \
        y2[2] = y1[2]; y1[2] = yy2;                                              \
        SUMV = (yy0 + yy1 + yy2);                                                \
    }

// ================= cooperative single-round kernel =================
// CCH=128: 256 rows x 4 segs = 1024 blocks x 256 thr (4 blocks/CU via 33.8KB LDS).
// ONE round -> exactly 2 grid.syncs:
//   p1(zero-state, x read #1) -> sync -> p2(256 parallel row scans) -> sync ->
//   p3(x read #2 = L3-served, LDS-staged quarter output)

#define TPB3C  256
#define CCH3   128
#define CPR3   (S_LEN / CCH3)      // 1024 chunks per row
#define SEGS3  (CPR3 / TPB3C)      // 4 blocks per row
#define GRID3  (SEGS3 * BATCHES)   // 1024 blocks
#define FOLD3  (CPR3 / 64)         // 16 chunks folded per scan lane
#define PSTR3  (CPR3 + CPR3 / 32)  // 1056: padded phase-2 LDS stride
#define LSTR3C 33                  // phase-3 quarter staging stride (32 samples + pad)

__global__ __launch_bounds__(TPB3C, 4)
void coop2_kernel(const float* __restrict__ x, const float* __restrict__ lvl,
                  float* __restrict__ out, float* __restrict__ ws)
{
    cg::grid_group grid = cg::this_grid();
    __shared__ float smem[TPB3C * LSTR3C];   // 33792 B; phase 2 uses first 6*1056=6336 floats

    const int tid = threadIdx.x;
    const int bid = blockIdx.x;
    const int seg = bid & (SEGS3 - 1);
    const int row = bid >> 2;

    float b0[3], na1[3], na2[3];
    compute_coeffs(lvl[row], b0, na1, na2);

    const int c = seg * TPB3C + tid;                 // chunk index within row, 0..1023
    const float* xc = x + (size_t)row * S_LEN + (size_t)c * CCH3;
    float xm1_0 = 0.f, xm2_0 = 0.f;
    if (c > 0) { float2 t = *(const float2*)(xc - 2); xm2_0 = t.x; xm1_0 = t.y; }

    float* wrow = ws + (size_t)row * 6 * CPR3;
    const float4* xv = (const float4*)xc;

    // -------- phase 1: zero-state response (x read #1, rolling 4-deep prefetch) --------
    {
        float y1[3] = {0.f,0.f,0.f}, y2[3] = {0.f,0.f,0.f};
        float p1 = xm1_0, p2 = xm2_0, dummy;
        float4 buf[4];
        #pragma unroll
        for (int j = 0; j < 4; ++j) buf[j] = xv[j];
        #pragma unroll
        for (int i = 0; i < CCH3 / 4; ++i) {
            float4 q = buf[i & 3];
            if (i + 4 < CCH3 / 4) buf[i & 3] = xv[i + 4];
            STEP3(q.x, p2, dummy)
            STEP3(q.y, p1, dummy)
            STEP3(q.z, q.x, dummy)
            STEP3(q.w, q.y, dummy)
            p2 = q.z; p1 = q.w;
        }
        (void)dummy;
        wrow[0 * CPR3 + c] = y1[0]; wrow[1 * CPR3 + c] = y2[0];
        wrow[2 * CPR3 + c] = y1[1]; wrow[3 * CPR3 + c] = y2[1];
        wrow[4 * CPR3 + c] = y1[2]; wrow[5 * CPR3 + c] = y2[2];
    }

    grid.sync();

    // -------- phase 2: blocks 0..255 each scan one row --------
    if (bid < BATCHES) {
        const int srow = bid;
        float* srw = ws + (size_t)srow * 6 * CPR3;

        // stage states in (coalesced global, padded LDS)
        #pragma unroll
        for (int e = 0; e < 6; ++e)
            for (int i = tid; i < CPR3; i += TPB3C)
                smem[e * PSTR3 + i + (i >> 5)] = srw[e * CPR3 + i];
        __syncthreads();

        const int wv = tid >> 6, ln = tid & 63;
        if (wv < 3) {
            float sb0[3], sa1[3], sa2[3];
            compute_coeffs(lvl[srow], sb0, sa1, sa2);
            const float A1 = sa1[wv], A2 = sa2[wv];

            // homogeneous solution over one chunk -> H
            float hm1 = 1.f, hm2 = 0.f, hm3 = 0.f;
            for (int i = 0; i < CCH3; ++i) {
                float h = fmaf(A1, hm1, A2 * hm2);
                hm3 = hm2; hm2 = hm1; hm1 = h;
            }
            const float H00 = hm1, H01 = A2 * hm2;
            const float H10 = hm2, H11 = A2 * hm3;

            float* z1p = smem + (2 * wv) * PSTR3;
            float* z2p = smem + (2 * wv + 1) * PSTR3;

            // fold this lane's 16 chunks
            float s1 = 0.f, s2 = 0.f;
            #pragma unroll
            for (int j = 0; j < FOLD3; ++j) {
                int cc = ln * FOLD3 + j, ca = cc + (cc >> 5);
                float z1 = z1p[ca], z2 = z2p[ca];
                float n1 = z1 + H00 * s1 + H01 * s2;
                float n2 = z2 + H10 * s1 + H11 * s2;
                s1 = n1; s2 = n2;
            }
            // A = H^16 via 4 squarings
            float P00 = H00, P01 = H01, P10 = H10, P11 = H11;
            #pragma unroll
            for (int t = 0; t < 4; ++t) {
                float Q00 = P00 * P00 + P01 * P10;
                float Q01 = P00 * P01 + P01 * P11;
                float Q10 = P10 * P00 + P11 * P10;
                float Q11 = P10 * P01 + P11 * P11;
                P00 = Q00; P01 = Q01; P10 = Q10; P11 = Q11;
            }
            // Kogge-Stone inclusive scan of affine maps across 64 lanes
            float A00 = P00, A01 = P01, A10 = P10, A11 = P11, bb1 = s1, bb2 = s2;
            for (int d = 1; d < 64; d <<= 1) {
                float iA00 = __shfl_up(A00, d), iA01 = __shfl_up(A01, d);
                float iA10 = __shfl_up(A10, d), iA11 = __shfl_up(A11, d);
                float ib1  = __shfl_up(bb1, d), ib2  = __shfl_up(bb2, d);
                if (ln >= d) {
                    float nb1 = A00 * ib1 + A01 * ib2 + bb1;
                    float nb2 = A10 * ib1 + A11 * ib2 + bb2;
                    float n00 = A00 * iA00 + A01 * iA10;
                    float n01 = A00 * iA01 + A01 * iA11;
                    float n10 = A10 * iA00 + A11 * iA10;
                    float n11 = A10 * iA01 + A11 * iA11;
                    A00 = n00; A01 = n01; A10 = n10; A11 = n11;
                    bb1 = nb1; bb2 = nb2;
                }
            }
            float e1 = __shfl_up(bb1, 1), e2 = __shfl_up(bb2, 1);
            if (ln == 0) { e1 = 0.f; e2 = 0.f; }

            // replay: overwrite zs with corrected chunk-ENTRY states
            s1 = e1; s2 = e2;
            #pragma unroll
            for (int j = 0; j < FOLD3; ++j) {
                int cc = ln * FOLD3 + j, ca = cc + (cc >> 5);
                float z1 = z1p[ca], z2 = z2p[ca];
                z1p[ca] = s1; z2p[ca] = s2;
                float n1 = z1 + H00 * s1 + H01 * s2;
                float n2 = z2 + H10 * s1 + H11 * s2;
                s1 = n1; s2 = n2;
            }
        }
        __syncthreads();

        // stage corrected states out (coalesced)
        #pragma unroll
        for (int e = 0; e < 6; ++e)
            for (int i = tid; i < CPR3; i += TPB3C)
                srw[e * CPR3 + i] = smem[e * PSTR3 + i + (i >> 5)];
    }

    grid.sync();

    // -------- phase 3: recurrence with corrected entry (x read #2, L3-served) --------
    {
        float y1[3], y2[3];
        y1[0] = wrow[0 * CPR3 + c]; y2[0] = wrow[1 * CPR3 + c];
        y1[1] = wrow[2 * CPR3 + c]; y2[1] = wrow[3 * CPR3 + c];
        y1[2] = wrow[4 * CPR3 + c]; y2[2] = wrow[5 * CPR3 + c];

        float p1 = xm1_0, p2 = xm2_0;
        const float is3 = 0.57735026918962576f;   // 1/sqrt(3)
        float* myob = smem + tid * LSTR3C;
        // block's output region: 256 chunks x 128 samples = 32768 samples
        float4* obase = (float4*)(out + (size_t)row * S_LEN + (size_t)seg * (TPB3C * CCH3));

        float4 buf[4];
        #pragma unroll
        for (int j = 0; j < 4; ++j) buf[j] = xv[j];

        for (int q = 0; q < 4; ++q) {            // quarter = 32 samples/thread
            #pragma unroll
            for (int i8 = 0; i8 < 8; ++i8) {
                int i = q * 8 + i8;
                float4 qd = buf[i & 3];
                if (i + 4 < CCH3 / 4) buf[i & 3] = xv[i + 4];
                float4 o;
                STEP3(qd.x, p2, o.x)
                STEP3(qd.y, p1, o.y)
                STEP3(qd.z, qd.x, o.z)
                STEP3(qd.w, qd.y, o.w)
                p2 = qd.z; p1 = qd.w;
                // bank = (tid + 4*i8 + k) % 32 -> 2-way aliasing (free)
                myob[4 * i8 + 0] = o.x * is3;
                myob[4 * i8 + 1] = o.y * is3;
                myob[4 * i8 + 2] = o.z * is3;
                myob[4 * i8 + 3] = o.w * is3;
            }
            __syncthreads();
            // cooperative store: 2048 float4 (32 KB), full 64B lines (8x128B clusters/instr)
            #pragma unroll
            for (int j = 0; j < 8; ++j) {
                int f   = j * TPB3C + tid;
                int ch  = f >> 3;                 // local chunk
                int off = f & 7;                  // float4 within quarter
                const float* p = smem + ch * LSTR3C + off * 4;
                float4 o = { p[0], p[1], p[2], p[3] };
                obase[(size_t)ch * (CCH3 / 4) + q * 8 + off] = o;
            }
            __syncthreads();
        }
    }
}

// ================= fallback 3-kernel path (round-3 code, known-good) =================

template<int CHUNK>
__global__ __launch_bounds__(256)
void k1_zerostate(const float* __restrict__ x, const float* __restrict__ level_arr,
                  float* __restrict__ ws)
{
    constexpr int CPR = S_LEN / CHUNK;
    constexpr int NV  = CHUNK / 4;
    const int g   = blockIdx.x * 256 + threadIdx.x;
    const int row = g / CPR;
    const int c   = g & (CPR - 1);

    float b0[3], na1[3], na2[3];
    compute_coeffs(level_arr[row], b0, na1, na2);

    const float* xc = x + (size_t)row * S_LEN + (size_t)c * CHUNK;
    float xm1 = 0.f, xm2 = 0.f;
    if (c > 0) { float2 t = *(const float2*)(xc - 2); xm2 = t.x; xm1 = t.y; }

    float y1[3] = {0.f,0.f,0.f}, y2[3] = {0.f,0.f,0.f};
    const float4* xv = (const float4*)xc;
    float4 buf[4];
    #pragma unroll
    for (int j = 0; j < 4; ++j) buf[j] = xv[j];
    float dummy;
    #pragma unroll
    for (int i = 0; i < NV; ++i) {
        float4 q = buf[i & 3];
        if (i + 4 < NV) buf[i & 3] = xv[i + 4];
        STEP3(q.x, xm2, dummy)
        STEP3(q.y, xm1, dummy)
        STEP3(q.z, q.x, dummy)
        STEP3(q.w, q.y, dummy)
        xm2 = q.z; xm1 = q.w;
    }
    (void)dummy;

    float* wrow = ws + (size_t)row * 6 * CPR;
    wrow[0 * CPR + c] = y1[0]; wrow[1 * CPR + c] = y2[0];
    wrow[2 * CPR + c] = y1[1]; wrow[3 * CPR + c] = y2[1];
    wrow[4 * CPR + c] = y1[2]; wrow[5 * CPR + c] = y2[2];
}

template<int CHUNK>
__global__ __launch_bounds__(192)
void k2_scan(const float* __restrict__ level_arr, float* __restrict__ ws)
{
    constexpr int CPR  = S_LEN / CHUNK;
    constexpr int FOLD = CPR / 64;
    constexpr int LSTRK = CPR + CPR / 32;
    __shared__ float st[6 * LSTRK];

    const int row  = blockIdx.x;
    const int wave = threadIdx.x >> 6;
    const int lane = threadIdx.x & 63;

    float b0[3], na1[3], na2[3];
    compute_coeffs(level_arr[row], b0, na1, na2);
    const float A1 = (wave == 0) ? na1[0] : ((wave == 1) ? na1[1] : na1[2]);
    const float A2 = (wave == 0) ? na2[0] : ((wave == 1) ? na2[1] : na2[2]);

    float* wrow = ws + (size_t)row * 6 * CPR;

    #pragma unroll
    for (int e = 2 * wave; e <= 2 * wave + 1; ++e)
        for (int i = lane; i < CPR; i += 64)
            st[e * LSTRK + i + (i >> 5)] = wrow[e * CPR + i];
    __syncthreads();

    float hm1 = 1.f, hm2 = 0.f, hm3 = 0.f;
    for (int i = 0; i < CHUNK; ++i) {
        float h = fmaf(A1, hm1, A2 * hm2);
        hm3 = hm2; hm2 = hm1; hm1 = h;
    }
    const float H00 = hm1, H01 = A2 * hm2;
    const float H10 = hm2, H11 = A2 * hm3;

    float* z1p = st + (2 * wave) * LSTRK;
    float* z2p = st + (2 * wave + 1) * LSTRK;

    float s1 = 0.f, s2 = 0.f;
    #pragma unroll
    for (int j = 0; j < FOLD; ++j) {
        int cc = lane * FOLD + j, ca = cc + (cc >> 5);
        float z1 = z1p[ca], z2 = z2p[ca];
        float n1 = z1 + H00 * s1 + H01 * s2;
        float n2 = z2 + H10 * s1 + H11 * s2;
        s1 = n1; s2 = n2;
    }
    float P00 = H00, P01 = H01, P10 = H10, P11 = H11;
    #pragma unroll
    for (int t = 0; (1 << t) < FOLD; ++t) {
        float Q00 = P00 * P00 + P01 * P10;
        float Q01 = P00 * P01 + P01 * P11;
        float Q10 = P10 * P00 + P11 * P10;
        float Q11 = P10 * P01 + P11 * P11;
        P00 = Q00; P01 = Q01; P10 = Q10; P11 = Q11;
    }
    float A00 = P00, A01 = P01, A10 = P10, A11 = P11, bb1 = s1, bb2 = s2;
    for (int d = 1; d < 64; d <<= 1) {
        float iA00 = __shfl_up(A00, d), iA01 = __shfl_up(A01, d);
        float iA10 = __shfl_up(A10, d), iA11 = __shfl_up(A11, d);
        float ib1  = __shfl_up(bb1, d), ib2  = __shfl_up(bb2, d);
        if (lane >= d) {
            float nb1 = A00 * ib1 + A01 * ib2 + bb1;
            float nb2 = A10 * ib1 + A11 * ib2 + bb2;
            float n00 = A00 * iA00 + A01 * iA10;
            float n01 = A00 * iA01 + A01 * iA11;
            float n10 = A10 * iA00 + A11 * iA10;
            float n11 = A10 * iA01 + A11 * iA11;
            A00 = n00; A01 = n01; A10 = n10; A11 = n11;
            bb1 = nb1; bb2 = nb2;
        }
    }
    float e1 = __shfl_up(bb1, 1), e2 = __shfl_up(bb2, 1);
    if (lane == 0) { e1 = 0.f; e2 = 0.f; }

    s1 = e1; s2 = e2;
    #pragma unroll
    for (int j = 0; j < FOLD; ++j) {
        int cc = lane * FOLD + j, ca = cc + (cc >> 5);
        float z1 = z1p[ca], z2 = z2p[ca];
        z1p[ca] = s1; z2p[ca] = s2;
        float n1 = z1 + H00 * s1 + H01 * s2;
        float n2 = z2 + H10 * s1 + H11 * s2;
        s1 = n1; s2 = n2;
    }
    __syncthreads();

    #pragma unroll
    for (int e = 2 * wave; e <= 2 * wave + 1; ++e)
        for (int i = lane; i < CPR; i += 64)
            wrow[e * CPR + i] = st[e * LSTRK + i + (i >> 5)];
}

__global__ __launch_bounds__(256)
void k3_apply_staged(const float* __restrict__ x, const float* __restrict__ level_arr,
                     const float* __restrict__ ws, float* __restrict__ out)
{
    constexpr int CHUNK = 64;
    constexpr int CPR   = S_LEN / CHUNK;
    constexpr int TPB3  = 256;
    constexpr int BPR   = CPR / TPB3;
    constexpr int NV    = CHUNK / 4;
    constexpr int LSTR3 = CHUNK + 1;
    __shared__ float ob[TPB3 * LSTR3];

    const int tid = threadIdx.x;
    const int row = blockIdx.x / BPR;
    const int seg = blockIdx.x % BPR;
    const int c   = seg * TPB3 + tid;

    float b0[3], na1[3], na2[3];
    compute_coeffs(level_arr[row], b0, na1, na2);

    const float* wrow = ws + (size_t)row * 6 * CPR;
    float y1[3], y2[3];
    y1[0] = wrow[0 * CPR + c]; y2[0] = wrow[1 * CPR + c];
    y1[1] = wrow[2 * CPR + c]; y2[1] = wrow[3 * CPR + c];
    y1[2] = wrow[4 * CPR + c]; y2[2] = wrow[5 * CPR + c];

    const float* xc = x + (size_t)row * S_LEN + (size_t)c * CHUNK;
    float xm1 = 0.f, xm2 = 0.f;
    if (c > 0) { float2 t = *(const float2*)(xc - 2); xm2 = t.x; xm1 = t.y; }

    const float4* xv = (const float4*)xc;
    const float inv_sqrt_nb = 0.57735026918962576f;
    float* myob = ob + tid * LSTR3;

    float4 buf[4];
    #pragma unroll
    for (int j = 0; j < 4; ++j) buf[j] = xv[j];
    #pragma unroll
    for (int i = 0; i < NV; ++i) {
        float4 q = buf[i & 3];
        if (i + 4 < NV) buf[i & 3] = xv[i + 4];
        float4 o;
        STEP3(q.x, xm2, o.x)
        STEP3(q.y, xm1, o.y)
        STEP3(q.z, q.x, o.z)
        STEP3(q.w, q.y, o.w)
        xm2 = q.z; xm1 = q.w;
        myob[4 * i + 0] = o.x * inv_sqrt_nb;
        myob[4 * i + 1] = o.y * inv_sqrt_nb;
        myob[4 * i + 2] = o.z * inv_sqrt_nb;
        myob[4 * i + 3] = o.w * inv_sqrt_nb;
    }
    __syncthreads();

    float4* obase = (float4*)(out + (size_t)row * S_LEN + (size_t)seg * (TPB3 * CHUNK));
    #pragma unroll
    for (int j = 0; j < NV; ++j) {
        int f = j * TPB3 + tid;
        int i = f * 4;
        int ch = i >> 6, off = i & 63;
        const float* p = ob + ch * LSTR3 + off;
        float4 o = { p[0], p[1], p[2], p[3] };
        obase[f] = o;
    }
}

static void launch_fallback(const float* audio, const float* level, float* out,
                            float* ws, hipStream_t stream)
{
    constexpr int CHUNK = 64;
    constexpr int CPR = S_LEN / CHUNK;
    const int total_threads = BATCHES * CPR;
    k1_zerostate<CHUNK><<<total_threads / 256, 256, 0, stream>>>(audio, level, ws);
    k2_scan<CHUNK><<<BATCHES, 192, 0, stream>>>(level, ws);
    k3_apply_staged<<<total_threads / 256, 256, 0, stream>>>(audio, level, ws, out);
}

// ================= launch =================

extern "C" void kernel_launch(void* const* d_in, const int* in_sizes, int n_in,
                              void* d_out, int out_size, void* d_ws, size_t ws_size,
                              hipStream_t stream) {
    const float* audio = (const float*)d_in[0];
    const float* level = (const float*)d_in[1];
    float* out = (float*)d_out;
    float* ws  = (float*)d_ws;
    (void)in_sizes; (void)n_in; (void)out_size;

    const size_t need_coop = (size_t)BATCHES * 6 * CPR3 * sizeof(float);   // 6.3 MB
    const size_t need_fb   = (size_t)BATCHES * 6 * (S_LEN / 64) * sizeof(float);

    int dev = 0;
    hipGetDevice(&dev);
    int coop = 0;
    hipDeviceGetAttribute(&coop, hipDeviceAttributeCooperativeLaunch, dev);
    int occ = 0;
    hipError_t oe = hipOccupancyMaxActiveBlocksPerMultiprocessor(&occ, coop2_kernel, TPB3C, 0);

    bool launched = false;
    if (coop && oe == hipSuccess && occ >= 4 && ws_size >= need_coop) {
        void* args[] = { (void*)&audio, (void*)&level, (void*)&out, (void*)&ws };
        hipError_t le = hipLaunchCooperativeKernel((const void*)coop2_kernel,
                                                   dim3(GRID3), dim3(TPB3C),
                                                   args, 0, stream);
        launched = (le == hipSuccess);
    }
    if (!launched && ws_size >= need_fb)
        launch_fallback(audio, level, out, ws, stream);
}

// Round 7
// 67.133 us; speedup vs baseline: 1.4727x; 1.4599x over previous
//
#include <hip/hip_runtime.h>
#include <math.h>

#ifndef M_PI
#define M_PI 3.14159265358979323846
#endif

#define BATCHES 256
#define S_LEN   131072

// One kernel, fully independent blocks (truncated-warmup linear recurrence).
// Block = 256 threads x 64-sample chunks = 16384-sample segment.
// Warmup: 16 extra chunks (1024 samples) before the segment, zero-state start;
// worst pole radius 0.9894 -> forgotten-state error ~2e-4 (threshold 2e-2).
#define TPB   256
#define CCH   64
#define SEGS  8                      // segments per row
#define SEG_SAMPS (TPB * CCH)        // 16384
#define WCH   16                     // warmup chunks
#define WIN   (TPB + WCH)            // 272 window chunks
#define PSTR  288                    // padded per-band state stride (chunks)
#define OBSTR 33                     // output staging stride (32 samples + pad)

__device__ __forceinline__ void compute_coeffs(float level_in, float b0[3], float na1[3], float na2[3]) {
    const float FD[3] = {270.0f, 800.0f, 2300.0f};
    const float FN[3] = {500.0f, 1500.0f, 2500.0f};
    const float FB[3] = {730.0f, 2100.0f, 3000.0f};
    float level = fminf(fmaxf(level_in, 0.0f), 1.0f);
    float t_low  = fminf(fmaxf(level * 2.0f, 0.0f), 1.0f);
    float t_high = fminf(fmaxf((level - 0.5f) * 2.0f, 0.0f), 1.0f);
    bool hi = (level >= 0.5f);
    const float W0 = (float)(2.0 * M_PI / 16000.0);
    #pragma unroll
    for (int k = 0; k < 3; ++k) {
        float f, q;
        if (hi) { f = (1.0f - t_high) * FN[k] + t_high * FB[k];
                  q = (1.0f - t_high) * 8.0f  + t_high * 12.0f; }
        else    { f = (1.0f - t_low) * FD[k] + t_low * FN[k];
                  q = (1.0f - t_low) * 5.0f  + t_low * 8.0f; }
        float omega = W0 * f;
        float sn = sinf(omega), cs = cosf(omega);
        float alpha = sn / (2.0f * fmaxf(q, 0.5f));
        float a0 = 1.0f + alpha;
        b0[k]  = alpha / a0;             // b2 == -b0 exactly
        na1[k] = (2.0f * cs) / a0;       // -a1
        na2[k] = -((1.0f - alpha) / a0); // -a2
    }
}

#define STEP3(XT, XTM2, SUMV)                                                    \
    {                                                                            \
        float d = (XT) - (XTM2);                                                 \
        float e0 = fmaf(b0[0], d, na2[0] * y2[0]);                               \
        float e1 = fmaf(b0[1], d, na2[1] * y2[1]);                               \
        float e2 = fmaf(b0[2], d, na2[2] * y2[2]);                               \
        float yy0 = fmaf(na1[0], y1[0], e0);                                     \
        float yy1 = fmaf(na1[1], y1[1], e1);                                     \
        float yy2 = fmaf(na1[2], y1[2], e2);                                     \
        y2[0] = y1[0]; y1[0] = yy0;                                              \
        y2[1] = y1[1]; y1[1] = yy1;                                              \
        y2[2] = y1[2]; y1[2] = yy2;                                              \
        SUMV = (yy0 + yy1 + yy2);                                                \
    }

// 2x2 matrix multiply: R = X * Y
#define MMUL(R00,R01,R10,R11, X00,X01,X10,X11, Y00,Y01,Y10,Y11)                  \
    {                                                                            \
        R00 = X00*Y00 + X01*Y10; R01 = X00*Y01 + X01*Y11;                        \
        R10 = X10*Y00 + X11*Y10; R11 = X10*Y01 + X11*Y11;                        \
    }

__global__ __launch_bounds__(TPB, 4)
void formant_onepass(const float* __restrict__ x, const float* __restrict__ lvl,
                     float* __restrict__ out)
{
    __shared__ float lds[TPB * OBSTR];   // 33792 B; scan uses first 6*288=1728 floats

    const int tid = threadIdx.x;
    const int row = blockIdx.x >> 3;
    const int seg = blockIdx.x & (SEGS - 1);

    float b0[3], na1[3], na2[3];
    compute_coeffs(lvl[row], b0, na1, na2);

    const float* xrow = x + (size_t)row * S_LEN;
    const size_t segBase = (size_t)seg * SEG_SAMPS;
    const float* xc = xrow + segBase + (size_t)tid * CCH;

    float xm1 = 0.f, xm2 = 0.f;
    if (seg > 0 || tid > 0) { float2 t2 = *(const float2*)(xc - 2); xm2 = t2.x; xm1 = t2.y; }

    // main chunk x -> registers (64 floats); compiler may rematerialize for p3
    float4 bufm[16];
    #pragma unroll
    for (int j = 0; j < 16; ++j) bufm[j] = ((const float4*)xc)[j];

    // -------- phase 1a: main-chunk zero-state --------
    {
        float y1[3] = {0.f,0.f,0.f}, y2[3] = {0.f,0.f,0.f};
        float p1 = xm1, p2 = xm2, dummy;
        #pragma unroll
        for (int i = 0; i < 16; ++i) {
            float4 q = bufm[i];
            STEP3(q.x, p2, dummy)
            STEP3(q.y, p1, dummy)
            STEP3(q.z, q.x, dummy)
            STEP3(q.w, q.y, dummy)
            p2 = q.z; p1 = q.w;
        }
        (void)dummy;
        lds[0*PSTR + WCH + tid] = y1[0]; lds[1*PSTR + WCH + tid] = y2[0];
        lds[2*PSTR + WCH + tid] = y1[1]; lds[3*PSTR + WCH + tid] = y2[1];
        lds[4*PSTR + WCH + tid] = y1[2]; lds[5*PSTR + WCH + tid] = y2[2];
    }

    // -------- phase 1b: warmup chunks (threads 0..15) --------
    if (tid < WCH) {
        if (seg == 0) {
            #pragma unroll
            for (int e = 0; e < 6; ++e) lds[e*PSTR + tid] = 0.f;   // exact: true zero state
        } else {
            const float* xw = xrow + segBase - (size_t)(WCH * CCH) + (size_t)tid * CCH;
            float2 t2 = *(const float2*)(xw - 2);
            float y1[3] = {0.f,0.f,0.f}, y2[3] = {0.f,0.f,0.f};
            float p2 = t2.x, p1 = t2.y, dummy;
            const float4* xv = (const float4*)xw;
            float4 buf[4];
            #pragma unroll
            for (int j = 0; j < 4; ++j) buf[j] = xv[j];
            #pragma unroll
            for (int i = 0; i < 16; ++i) {
                float4 q = buf[i & 3];
                if (i + 4 < 16) buf[i & 3] = xv[i + 4];
                STEP3(q.x, p2, dummy)
                STEP3(q.y, p1, dummy)
                STEP3(q.z, q.x, dummy)
                STEP3(q.w, q.y, dummy)
                p2 = q.z; p1 = q.w;
            }
            (void)dummy;
            lds[0*PSTR + tid] = y1[0]; lds[1*PSTR + tid] = y2[0];
            lds[2*PSTR + tid] = y1[1]; lds[3*PSTR + tid] = y2[1];
            lds[4*PSTR + tid] = y1[2]; lds[5*PSTR + tid] = y2[2];
        }
    }
    __syncthreads();

    // -------- phase 2: block-local affine scan over 272 chunk states --------
    // lane l folds cnt chunks: lanes 0..15 -> 5 chunks, lanes 16..63 -> 4 (16*5+48*4=272)
    {
        const int wv = tid >> 6, ln = tid & 63;
        if (wv < 3) {
            const float A1 = na1[wv], A2 = na2[wv];
            // homogeneous solution over one chunk -> H
            float hm1 = 1.f, hm2 = 0.f, hm3 = 0.f;
            for (int i = 0; i < CCH; ++i) {
                float h = fmaf(A1, hm1, A2 * hm2);
                hm3 = hm2; hm2 = hm1; hm1 = h;
            }
            const float H00 = hm1, H01 = A2 * hm2;
            const float H10 = hm2, H11 = A2 * hm3;

            float* z1p = lds + (2*wv) * PSTR;
            float* z2p = lds + (2*wv + 1) * PSTR;

            const int cnt = (ln < 16) ? 5 : 4;
            const int beg = (ln < 16) ? 5 * ln : 80 + 4 * (ln - 16);

            // fold
            float s1 = 0.f, s2 = 0.f;
            for (int j = 0; j < cnt; ++j) {
                float z1 = z1p[beg + j], z2 = z2p[beg + j];
                float n1 = z1 + H00 * s1 + H01 * s2;
                float n2 = z2 + H10 * s1 + H11 * s2;
                s1 = n1; s2 = n2;
            }
            // A_l = H^cnt
            float B00,B01,B10,B11, C00,C01,C10,C11;
            MMUL(B00,B01,B10,B11, H00,H01,H10,H11, H00,H01,H10,H11)   // H^2
            MMUL(C00,C01,C10,C11, B00,B01,B10,B11, B00,B01,B10,B11)   // H^4
            float A00 = C00, A01 = C01, A10 = C10, A11 = C11;
            if (cnt == 5) {
                float D00,D01,D10,D11;
                MMUL(D00,D01,D10,D11, C00,C01,C10,C11, H00,H01,H10,H11)
                A00 = D00; A01 = D01; A10 = D10; A11 = D11;
            }
            // Kogge-Stone inclusive scan of affine maps
            float bb1 = s1, bb2 = s2;
            for (int d = 1; d < 64; d <<= 1) {
                float iA00 = __shfl_up(A00, d), iA01 = __shfl_up(A01, d);
                float iA10 = __shfl_up(A10, d), iA11 = __shfl_up(A11, d);
                float ib1  = __shfl_up(bb1, d), ib2  = __shfl_up(bb2, d);
                if (ln >= d) {
                    float nb1 = A00 * ib1 + A01 * ib2 + bb1;
                    float nb2 = A10 * ib1 + A11 * ib2 + bb2;
                    float n00, n01, n10, n11;
                    MMUL(n00,n01,n10,n11, A00,A01,A10,A11, iA00,iA01,iA10,iA11)
                    A00 = n00; A01 = n01; A10 = n10; A11 = n11;
                    bb1 = nb1; bb2 = nb2;
                }
            }
            float e1 = __shfl_up(bb1, 1), e2 = __shfl_up(bb2, 1);
            if (ln == 0) { e1 = 0.f; e2 = 0.f; }

            // replay: overwrite z with corrected chunk-ENTRY states
            s1 = e1; s2 = e2;
            for (int j = 0; j < cnt; ++j) {
                int w = beg + j;
                float z1 = z1p[w], z2 = z2p[w];
                z1p[w] = s1; z2p[w] = s2;
                float n1 = z1 + H00 * s1 + H01 * s2;
                float n2 = z2 + H10 * s1 + H11 * s2;
                s1 = n1; s2 = n2;
            }
        }
    }
    __syncthreads();

    // -------- phase 3: recurrence with corrected entry; LDS-staged coalesced out --------
    float y1[3], y2[3];
    y1[0] = lds[0*PSTR + WCH + tid]; y2[0] = lds[1*PSTR + WCH + tid];
    y1[1] = lds[2*PSTR + WCH + tid]; y2[1] = lds[3*PSTR + WCH + tid];
    y1[2] = lds[4*PSTR + WCH + tid]; y2[2] = lds[5*PSTR + WCH + tid];
    __syncthreads();   // scan region now reusable as staging

    {
        float p1 = xm1, p2 = xm2;
        const float is3 = 0.57735026918962576f;   // 1/sqrt(3)
        float* myob = lds + tid * OBSTR;
        float4* obase = (float4*)(out + (size_t)row * S_LEN + segBase);

        #pragma unroll
        for (int h = 0; h < 2; ++h) {             // two 32-sample halves
            #pragma unroll
            for (int i8 = 0; i8 < 8; ++i8) {
                float4 q = bufm[h * 8 + i8];
                float4 o;
                STEP3(q.x, p2, o.x)
                STEP3(q.y, p1, o.y)
                STEP3(q.z, q.x, o.z)
                STEP3(q.w, q.y, o.w)
                p2 = q.z; p1 = q.w;
                // scalar LDS writes: bank=(tid+4*i8+k)%32 -> 2-way max (free)
                myob[4*i8 + 0] = o.x * is3;
                myob[4*i8 + 1] = o.y * is3;
                myob[4*i8 + 2] = o.z * is3;
                myob[4*i8 + 3] = o.w * is3;
            }
            __syncthreads();
            // cooperative store: 2048 float4 (32 KB), full 64B lines
            #pragma unroll
            for (int j = 0; j < 8; ++j) {
                int f   = j * TPB + tid;
                int ch  = f >> 3;                 // local chunk
                int off = f & 7;                  // float4 within half
                const float* p = lds + ch * OBSTR + off * 4;
                float4 o = { p[0], p[1], p[2], p[3] };
                obase[(size_t)ch * (CCH / 4) + h * 8 + off] = o;
            }
            __syncthreads();
        }
    }
}

extern "C" void kernel_launch(void* const* d_in, const int* in_sizes, int n_in,
                              void* d_out, int out_size, void* d_ws, size_t ws_size,
                              hipStream_t stream) {
    const float* audio = (const float*)d_in[0];
    const float* level = (const float*)d_in[1];
    float* out = (float*)d_out;
    (void)in_sizes; (void)n_in; (void)d_ws; (void)ws_size; (void)out_size;

    formant_onepass<<<BATCHES * SEGS, TPB, 0, stream>>>(audio, level, out);
}